// Round 10
// baseline (97.294 us; speedup 1.0000x reference)
//
#include <hip/hip_runtime.h>

#define NB    4
#define PPB   4096           // downsampled points per batch (64x64)
#define BLK   256
#define CHK   128            // points per triangle chunk
#define NCHK  32             // chunks per batch
#define NBLK3 528            // triangle blocks per batch: 32*33/2

#if __has_builtin(__builtin_amdgcn_exp2f)
#define EXPFN(x) __builtin_amdgcn_exp2f(x)
#define FSCALE 1.2011224087864498f   /* sqrt(log2(e)) */
#else
#define EXPFN(x) __expf(x)
#define FSCALE 1.0f
#endif

typedef __attribute__((ext_vector_type(8))) short short8v;   // 8 bf16 (4 VGPR)
typedef __attribute__((ext_vector_type(4))) float f32x4;

typedef unsigned int uint;
typedef unsigned short ushort;

// Round-to-nearest-even bf16 split: returns bf16 bits, rem = v - bf16(v) (exact).
__device__ __forceinline__ ushort bsplit(float v, float& rem) {
    uint u = __float_as_uint(v);
    uint r = (u + 0x7FFFu + ((u >> 16) & 1u)) >> 16;
    rem = v - __uint_as_float(r << 16);
    return (ushort)r;
}

// ws layout (per 16384 global points) -- byte-identical packing to the
// HW-verified R7/R8 kernels (absmax 0.0):
//   FA[p][32] bf16  feat K-vector, A-pattern [f1 f1 f2 f1 f2 f3 | 0 0]
//   FB[p][32] bf16  feat K-vector, B-pattern [f1 f2 f1 f3 f2 f1 | 0 0]
//   SA[p][32] bf16  seg  K-vector, A-pattern [t1 t1 t2 | 0...]
//   SB[p][32] bf16  seg  K-vector, B-pattern [t1 t2 t1 | 0...]
//   H [p]     f32   h = -0.5*|f^|^2 (log2 units; f^ = f*FSCALE)
// Launched as 256 blocks x 64 threads: spreads over all CUs (latency-bound).
__global__ __launch_bounds__(64) void crf_prep(const float* __restrict__ images,
                                               const float* __restrict__ segs,
                                               uint* __restrict__ FA,
                                               uint* __restrict__ FB,
                                               uint* __restrict__ SA,
                                               uint* __restrict__ SB,
                                               float* __restrict__ H,
                                               float* __restrict__ out) {
    int gid = blockIdx.x * 64 + threadIdx.x;    // 0..16383
    if (gid == 0) out[0] = 0.0f;                // replaces memset dispatch
    int n = gid >> 12;
    int p = gid & (PPB - 1);
    int i = p >> 6;
    int j = p & 63;
    int off = 256 * i + 2 * j;                  // pixel (2i,2j) in 128x128
    const float* img = images + (size_t)n * 3 * 16384;
    float f[5];
    f[0] = (float)j * (FSCALE / 50.0f);         // SIGMA_XY*SCALE = 50
    f[1] = (float)i * (FSCALE / 50.0f);
    f[2] = img[off]         * (FSCALE / 15.0f); // SIGMA_RGB = 15
    f[3] = img[16384 + off] * (FSCALE / 15.0f);
    f[4] = img[32768 + off] * (FSCALE / 15.0f);
    float h = -0.5f * (f[0]*f[0] + f[1]*f[1] + f[2]*f[2] + f[3]*f[3] + f[4]*f[4]);

    const float* sg = segs + (size_t)n * 4 * 16384;
    float s[4];
#pragma unroll
    for (int k = 0; k < 4; ++k) {
        float2 u0 = *(const float2*)(sg + k * 16384 + off);
        float2 u1 = *(const float2*)(sg + k * 16384 + off + 128);
        s[k] = 0.25f * ((u0.x + u0.y) + (u1.x + u1.y));
    }

    // 3-way bf16 split of feats, 2-way split of segs.
    ushort v[3][5];
    ushort tg[2][4];
#pragma unroll
    for (int c = 0; c < 5; ++c) {
        float r1, r2, dead;
        v[0][c] = bsplit(f[c], r1);
        v[1][c] = bsplit(r1, r2);
        v[2][c] = bsplit(r2, dead);
    }
#pragma unroll
    for (int c = 0; c < 4; ++c) {
        float r1, dead;
        tg[0][c] = bsplit(s[c], r1);
        tg[1][c] = bsplit(r1, dead);
    }

    static const int PA[6] = {0, 0, 1, 0, 1, 2};
    static const int PB[6] = {0, 1, 0, 2, 1, 0};
    uint fa[16], fb[16], sa[16], sb[16];
#pragma unroll
    for (int k2 = 0; k2 < 16; ++k2) {
        int s0 = 2 * k2, s1 = s0 + 1;
        uint lo = (s0 >= 30) ? 0u : (uint)v[PA[s0 / 5]][s0 % 5];
        uint hi = (s1 >= 30) ? 0u : (uint)v[PA[s1 / 5]][s1 % 5];
        fa[k2] = lo | (hi << 16);
        lo = (s0 >= 30) ? 0u : (uint)v[PB[s0 / 5]][s0 % 5];
        hi = (s1 >= 30) ? 0u : (uint)v[PB[s1 / 5]][s1 % 5];
        fb[k2] = lo | (hi << 16);
    }
    static const int QA[3] = {0, 0, 1};
    static const int QB[3] = {0, 1, 0};
#pragma unroll
    for (int k2 = 0; k2 < 16; ++k2) {
        int s0 = 2 * k2, s1 = s0 + 1;
        uint lo = (s0 >= 12) ? 0u : (uint)tg[QA[s0 / 4]][s0 % 4];
        uint hi = (s1 >= 12) ? 0u : (uint)tg[QA[s1 / 4]][s1 % 4];
        sa[k2] = lo | (hi << 16);
        lo = (s0 >= 12) ? 0u : (uint)tg[QB[s0 / 4]][s0 % 4];
        hi = (s1 >= 12) ? 0u : (uint)tg[QB[s1 / 4]][s1 % 4];
        sb[k2] = lo | (hi << 16);
    }

    uint4* fap = (uint4*)(FA + (size_t)gid * 16);
    uint4* fbp = (uint4*)(FB + (size_t)gid * 16);
    uint4* sap = (uint4*)(SA + (size_t)gid * 16);
    uint4* sbp = (uint4*)(SB + (size_t)gid * 16);
#pragma unroll
    for (int k = 0; k < 4; ++k) {
        fap[k] = make_uint4(fa[4*k], fa[4*k+1], fa[4*k+2], fa[4*k+3]);
        fbp[k] = make_uint4(fb[4*k], fb[4*k+1], fb[4*k+2], fb[4*k+3]);
        sap[k] = make_uint4(sa[4*k], sa[4*k+1], sa[4*k+2], sa[4*k+3]);
        sbp[k] = make_uint4(sb[4*k], sb[4*k+1], sb[4*k+2], sb[4*k+3]);
    }
    H[gid] = h;
}

// MFMA pair kernel (verified math, R8): 128x128 chunks, 4 waves/block, two
// resident A-fragment pairs per wave, 8 q-tiles. Changes vs R8: occupancy
// raised to 6 waves/SIMD (epilogue reordered so peak VGPR ~55), and the
// block result is atomicAdd'ed (reduce kernel deleted).
__global__ __launch_bounds__(256, 6) void crf_pairs(const uint4* __restrict__ FA,
                                                    const uint4* __restrict__ FB,
                                                    const uint4* __restrict__ SA,
                                                    const uint4* __restrict__ SB,
                                                    const float* __restrict__ H,
                                                    float* __restrict__ out) {
    __shared__ float wsum[BLK / 64];
    int t = threadIdx.x;
    int n = blockIdx.y;
    int lane = t & 63;
    int w = t >> 6;
    int l15 = lane & 15;
    int lhi = lane >> 4;

    // Decode triangle block -> (p-chunk pc, q-chunk qc), qc >= pc.
    int b = blockIdx.x;                  // 0..527
    int pc = 0;
#pragma unroll
    for (int i = 1; i < NCHK; ++i) pc += (b >= (i * (2 * NCHK + 1 - i)) / 2) ? 1 : 0;
    int qc = b - (pc * (2 * NCHK + 1 - pc)) / 2 + pc;
    bool diagblk = (pc == qc);
    int base = n << 12;
    int prow0 = pc * CHK + w * 32;       // wave's 32 p-rows

    // A-side fragments (resident for the whole kernel).
    size_t ar = (size_t)(base + prow0 + l15) * 4 + lhi;
    short8v a0  = __builtin_bit_cast(short8v, FA[ar]);
    short8v a1  = __builtin_bit_cast(short8v, FA[ar + 64]);     // +16 rows
    short8v sa0 = __builtin_bit_cast(short8v, SA[ar]);
    short8v sa1 = __builtin_bit_cast(short8v, SA[ar + 64]);
    float hp0[4], hp1[4];
#pragma unroll
    for (int r = 0; r < 4; ++r) {
        hp0[r] = H[base + prow0 + lhi * 4 + r];
        hp1[r] = H[base + prow0 + 16 + lhi * 4 + r];
    }

    float accP = 0.f;   // plain tiles (doubled at the end)
    float accD = 0.f;   // diagonal-chunk tiles (explicit 2/1/0 weights)

#pragma unroll
    for (int jj = 0; jj < 8; ++jj) {
        if (diagblk && jj < 2 * w) continue;   // q-tile fully below both frags
        int qrow0 = qc * CHK + jj * 16;
        size_t br = (size_t)(base + qrow0 + l15) * 4 + lhi;
        short8v bf  = __builtin_bit_cast(short8v, FB[br]);
        short8v sbf = __builtin_bit_cast(short8v, SB[br]);
        float hq = H[base + qrow0 + l15];

        // Frag-pair 0: MFMA then consume (keeps peak VGPR low for occupancy 6).
        f32x4 cf0 = {0.f, 0.f, 0.f, 0.f};
        f32x4 cs0 = {0.f, 0.f, 0.f, 0.f};
        cf0 = __builtin_amdgcn_mfma_f32_16x16x32_bf16(a0, bf, cf0, 0, 0, 0);
        cs0 = __builtin_amdgcn_mfma_f32_16x16x32_bf16(sa0, sbf, cs0, 0, 0, 0);

        if (!diagblk) {
#pragma unroll
            for (int r = 0; r < 4; ++r)
                accP = fmaf(EXPFN(cf0[r] + (hp0[r] + hq)), cs0[r], accP);
        } else {
            int ql = qrow0 + l15;
            int pl = prow0 + lhi * 4;
#pragma unroll
            for (int r = 0; r < 4; ++r) {
                float w0 = EXPFN(cf0[r] + (hp0[r] + hq));
                int pg0 = pl + r;
                float f0 = (ql > pg0) ? 2.0f : ((ql == pg0) ? 1.0f : 0.0f);
                accD = fmaf(w0 * f0, cs0[r], accD);
            }
        }

        // Frag-pair 1.
        f32x4 cf1 = {0.f, 0.f, 0.f, 0.f};
        f32x4 cs1 = {0.f, 0.f, 0.f, 0.f};
        cf1 = __builtin_amdgcn_mfma_f32_16x16x32_bf16(a1, bf, cf1, 0, 0, 0);
        cs1 = __builtin_amdgcn_mfma_f32_16x16x32_bf16(sa1, sbf, cs1, 0, 0, 0);

        if (!diagblk) {
#pragma unroll
            for (int r = 0; r < 4; ++r)
                accP = fmaf(EXPFN(cf1[r] + (hp1[r] + hq)), cs1[r], accP);
        } else {
            int ql = qrow0 + l15;
            int pl = prow0 + lhi * 4 + 16;
#pragma unroll
            for (int r = 0; r < 4; ++r) {
                float w1 = EXPFN(cf1[r] + (hp1[r] + hq));
                int pg1 = pl + r;
                float f1 = (ql > pg1) ? 2.0f : ((ql == pg1) ? 1.0f : 0.0f);
                accD = fmaf(w1 * f1, cs1[r], accD);
            }
        }
    }

    float acc_all = 2.0f * accP + accD;
#pragma unroll
    for (int off = 32; off > 0; off >>= 1)
        acc_all += __shfl_down(acc_all, off, 64);
    if ((t & 63) == 0) wsum[t >> 6] = acc_all;
    __syncthreads();
    if (t == 0) {
        float s = (wsum[0] + wsum[1]) + (wsum[2] + wsum[3]);
        // loss = WEIGHT * (-sum / n) = -1e-7/4 * sum
        atomicAdd(out, s * (-2.5e-8f));
    }
}

extern "C" void kernel_launch(void* const* d_in, const int* in_sizes, int n_in,
                              void* d_out, int out_size, void* d_ws, size_t ws_size,
                              hipStream_t stream) {
    const float* images = (const float*)d_in[0];
    const float* segs   = (const float*)d_in[1];
    float* out = (float*)d_out;
    char* ws = (char*)d_ws;
    uint* FA = (uint*)(ws);                     // 16384*64 B = 1 MiB
    uint* FB = (uint*)(ws + (1u << 20));        // 1 MiB
    uint* SA = (uint*)(ws + (2u << 20));        // 1 MiB
    uint* SB = (uint*)(ws + (3u << 20));        // 1 MiB
    float* H = (float*)(ws + (4u << 20));       // 64 KiB
    (void)in_sizes; (void)n_in; (void)out_size; (void)ws_size;

    crf_prep<<<dim3(256), dim3(64), 0, stream>>>(images, segs, FA, FB, SA, SB, H, out);
    crf_pairs<<<dim3(NBLK3, NB), dim3(256), 0, stream>>>(
        (const uint4*)FA, (const uint4*)FB, (const uint4*)SA, (const uint4*)SB, H, out);
}

// Round 11
// 73.860 us; speedup vs baseline: 1.3173x; 1.3173x over previous
//
#include <hip/hip_runtime.h>

#define NB   4
#define KCH  4
#define PPB  4096          // downsampled points per batch (64x64)
#define QT   32            // q per block
#define BLK  256           // threads per block
#define PT   2             // p per thread (p-tile = 512)
#define NBLK 576           // triangle blocks per batch: sum_{pt=0..7}(128-16*pt)
#define NPART (NBLK * NB)  // 2304 partials

#if __has_builtin(__builtin_amdgcn_exp2f)
#define EXPFN(x) __builtin_amdgcn_exp2f(x)
#define FSCALE 1.2011224087864498f   /* sqrt(log2(e)) */
#else
#define EXPFN(x) __expf(x)
#define FSCALE 1.0f
#endif

// Record layout (SoA over 16384 global points, ws-resident):
//   RA[p] = (x, y, r, g)      float4
//   RB[p] = (b, h, s0, s1)    float4   h = -0.5*|f|^2 (log2 units)
//   RC[p] = (s2, s3)          float2
// feats pre-scaled by FSCALE so exp2 needs no extra multiply.

__global__ __launch_bounds__(256) void crf_prep(const float* __restrict__ images,
                                                const float* __restrict__ segs,
                                                float4* __restrict__ RA,
                                                float4* __restrict__ RB,
                                                float2* __restrict__ RC) {
    int gid = blockIdx.x * BLK + threadIdx.x;   // 0..16383
    int n = gid >> 12;
    int p = gid & (PPB - 1);
    int i = p >> 6;
    int j = p & 63;
    int off = 256 * i + 2 * j;                  // pixel (2i, 2j) in 128x128
    const float* img = images + (size_t)n * 3 * 16384;
    float x = (float)j * (FSCALE / 50.0f);      // SIGMA_XY*SCALE = 50
    float y = (float)i * (FSCALE / 50.0f);
    float r = img[off]         * (FSCALE / 15.0f);   // SIGMA_RGB = 15
    float g = img[16384 + off] * (FSCALE / 15.0f);
    float b = img[32768 + off] * (FSCALE / 15.0f);
    float h = -0.5f * (x * x + y * y + r * r + g * g + b * b);
    const float* sg = segs + (size_t)n * KCH * 16384;
    float s0, s1, s2, s3;
    {
        float2 u0 = *(const float2*)(sg + off);
        float2 u1 = *(const float2*)(sg + off + 128);
        s0 = 0.25f * ((u0.x + u0.y) + (u1.x + u1.y));
        u0 = *(const float2*)(sg + 16384 + off);
        u1 = *(const float2*)(sg + 16384 + off + 128);
        s1 = 0.25f * ((u0.x + u0.y) + (u1.x + u1.y));
        u0 = *(const float2*)(sg + 32768 + off);
        u1 = *(const float2*)(sg + 32768 + off + 128);
        s2 = 0.25f * ((u0.x + u0.y) + (u1.x + u1.y));
        u0 = *(const float2*)(sg + 49152 + off);
        u1 = *(const float2*)(sg + 49152 + off + 128);
        s3 = 0.25f * ((u0.x + u0.y) + (u1.x + u1.y));
    }
    RA[gid] = make_float4(x, y, r, g);
    RB[gid] = make_float4(b, h, s0, s1);
    RC[gid] = make_float2(s2, s3);
}

// Pair kernel, max-occupancy: PT=2, QT=32, 2304 blocks (9 waves/SIMD demand),
// __launch_bounds__(256,8) pins VGPR <= 64 so 8 waves/SIMD are resident.
// No atomics: per-block partial to workspace. LDS broadcast reads per iter
// (latency hidden by 8-wave TLP, no prefetch registers needed).
__global__ __launch_bounds__(256, 8) void crf_pairs(const float4* __restrict__ RA,
                                                    const float4* __restrict__ RB,
                                                    const float2* __restrict__ RC,
                                                    float* __restrict__ part) {
    __shared__ float4 ldsA[QT];
    __shared__ float4 ldsB[QT];
    __shared__ float2 ldsC[QT];
    __shared__ float wsum[BLK / 64];

    int t = threadIdx.x;
    int n = blockIdx.y;

    // Decode triangle block index -> (p-tile pt of 512, q-chunk qc of 32),
    // qc >= 16*pt. counts per pt: 128-16*pt ; cum(pt) = 8*pt*(17-pt)
    int b = blockIdx.x;                  // 0..575
    int pt = 0;
#pragma unroll
    for (int i = 1; i < 8; ++i) pt += (b >= 8 * i * (17 - i)) ? 1 : 0;
    int qc = b - 8 * pt * (17 - pt) + 16 * pt;
    int pbase = pt * (BLK * PT);         // pt*512
    int qbase = qc * QT;
    bool mixed = (qc >> 4) == pt;        // q-chunk inside the p-tile
    int base = n << 12;

    // Stage q-records into LDS (one-time).
    if (t < QT)            ldsA[t]          = RA[base + qbase + t];
    else if (t < 2 * QT)   ldsB[t - QT]     = RB[base + qbase + (t - QT)];
    else if (t < 3 * QT)   ldsC[t - 2 * QT] = RC[base + qbase + (t - 2 * QT)];

    // p-records: PT=2 per thread, coalesced vector loads, named registers.
    float4 pa0 = RA[base + pbase + t];
    float4 pa1 = RA[base + pbase + t + BLK];
    float4 pb0 = RB[base + pbase + t];
    float4 pb1 = RB[base + pbase + t + BLK];
    float2 pc0 = RC[base + pbase + t];
    float2 pc1 = RC[base + pbase + t + BLK];
    __syncthreads();

    float acc0 = 0.f, acc1 = 0.f;
    float acc_all;

    if (!mixed) {
        // Strictly above the diagonal: every pair counts twice.
#pragma unroll 4
        for (int q = 0; q < QT; ++q) {
            float4 fa = ldsA[q];
            float4 fb = ldsB[q];
            float2 fc = ldsC[q];
            float d0 = pb0.y + fb.y;
            d0 = fmaf(pa0.x, fa.x, d0);
            d0 = fmaf(pa0.y, fa.y, d0);
            d0 = fmaf(pa0.z, fa.z, d0);
            d0 = fmaf(pa0.w, fa.w, d0);
            d0 = fmaf(pb0.x, fb.x, d0);
            float w0 = EXPFN(d0);
            float sd0 = pb0.z * fb.z;
            sd0 = fmaf(pb0.w, fb.w, sd0);
            sd0 = fmaf(pc0.x, fc.x, sd0);
            sd0 = fmaf(pc0.y, fc.y, sd0);
            acc0 = fmaf(w0, sd0, acc0);

            float d1 = pb1.y + fb.y;
            d1 = fmaf(pa1.x, fa.x, d1);
            d1 = fmaf(pa1.y, fa.y, d1);
            d1 = fmaf(pa1.z, fa.z, d1);
            d1 = fmaf(pa1.w, fa.w, d1);
            d1 = fmaf(pb1.x, fb.x, d1);
            float w1 = EXPFN(d1);
            float sd1 = pb1.z * fb.z;
            sd1 = fmaf(pb1.w, fb.w, sd1);
            sd1 = fmaf(pc1.x, fc.x, sd1);
            sd1 = fmaf(pc1.y, fc.y, sd1);
            acc1 = fmaf(w1, sd1, acc1);
        }
        acc_all = 2.0f * (acc0 + acc1);
    } else {
        // Diagonal-overlap block: weight pairs 2/1/0 for q>p / q==p / q<p.
        int pg0 = pbase + t;
        int pg1 = pbase + t + BLK;
#pragma unroll 4
        for (int q = 0; q < QT; ++q) {
            float4 fa = ldsA[q];
            float4 fb = ldsB[q];
            float2 fc = ldsC[q];
            int qg = qbase + q;
            float d0 = pb0.y + fb.y;
            d0 = fmaf(pa0.x, fa.x, d0);
            d0 = fmaf(pa0.y, fa.y, d0);
            d0 = fmaf(pa0.z, fa.z, d0);
            d0 = fmaf(pa0.w, fa.w, d0);
            d0 = fmaf(pb0.x, fb.x, d0);
            float w0 = EXPFN(d0);
            float sd0 = pb0.z * fb.z;
            sd0 = fmaf(pb0.w, fb.w, sd0);
            sd0 = fmaf(pc0.x, fc.x, sd0);
            sd0 = fmaf(pc0.y, fc.y, sd0);
            float f0 = (qg > pg0) ? 2.0f : ((qg == pg0) ? 1.0f : 0.0f);
            acc0 = fmaf(w0, sd0 * f0, acc0);

            float d1 = pb1.y + fb.y;
            d1 = fmaf(pa1.x, fa.x, d1);
            d1 = fmaf(pa1.y, fa.y, d1);
            d1 = fmaf(pa1.z, fa.z, d1);
            d1 = fmaf(pa1.w, fa.w, d1);
            d1 = fmaf(pb1.x, fb.x, d1);
            float w1 = EXPFN(d1);
            float sd1 = pb1.z * fb.z;
            sd1 = fmaf(pb1.w, fb.w, sd1);
            sd1 = fmaf(pc1.x, fc.x, sd1);
            sd1 = fmaf(pc1.y, fc.y, sd1);
            float f1 = (qg > pg1) ? 2.0f : ((qg == pg1) ? 1.0f : 0.0f);
            acc1 = fmaf(w1, sd1 * f1, acc1);
        }
        acc_all = acc0 + acc1;
    }

#pragma unroll
    for (int off = 32; off > 0; off >>= 1)
        acc_all += __shfl_down(acc_all, off, 64);
    if ((t & 63) == 0) wsum[t >> 6] = acc_all;
    __syncthreads();
    if (t == 0) {
        part[n * NBLK + blockIdx.x] =
            (wsum[0] + wsum[1]) + (wsum[2] + wsum[3]);
    }
}

// Final reduction: 2304 partials -> out[0], single block, no atomics.
__global__ __launch_bounds__(256) void crf_reduce(const float* __restrict__ part,
                                                  float* __restrict__ out) {
    __shared__ float wsum[BLK / 64];
    int t = threadIdx.x;
    float s = 0.f;
#pragma unroll
    for (int i = 0; i < NPART / BLK; ++i)       // 9 iterations, exact
        s += part[t + i * BLK];
#pragma unroll
    for (int off = 32; off > 0; off >>= 1)
        s += __shfl_down(s, off, 64);
    if ((t & 63) == 0) wsum[t >> 6] = s;
    __syncthreads();
    if (t == 0) {
        float tot = (wsum[0] + wsum[1]) + (wsum[2] + wsum[3]);
        // loss = WEIGHT * (-sum / n) = -1e-7/4 * sum
        out[0] = tot * (-2.5e-8f);
    }
}

extern "C" void kernel_launch(void* const* d_in, const int* in_sizes, int n_in,
                              void* d_out, int out_size, void* d_ws, size_t ws_size,
                              hipStream_t stream) {
    const float* images = (const float*)d_in[0];
    const float* segs   = (const float*)d_in[1];
    float* out = (float*)d_out;
    char* ws = (char*)d_ws;
    float4* RA = (float4*)(ws);                 // 16384 * 16 B = 256 KiB
    float4* RB = (float4*)(ws + 262144);        // 256 KiB
    float2* RC = (float2*)(ws + 524288);        // 128 KiB
    float* part = (float*)(ws + 655360);        // 2304 * 4 B
    (void)in_sizes; (void)n_in; (void)out_size; (void)ws_size;

    crf_prep<<<dim3(64), dim3(256), 0, stream>>>(images, segs, RA, RB, RC);
    crf_pairs<<<dim3(NBLK, NB), dim3(256), 0, stream>>>(RA, RB, RC, part);
    crf_reduce<<<dim3(1), dim3(256), 0, stream>>>(part, out);
}